// Round 16
// baseline (459.898 us; speedup 1.0000x reference)
//
#include <hip/hip_runtime.h>
#include <hip/hip_bf16.h>
#include <stdint.h>

#define N_ATOMS 65536
#define N_BONDS 131072
#define N_MOLS  512
#define D_IN    16
#define DD      128
#define REPEAT  3
#define PITCH   136   // LDS row pitch (bf16): 2-way max bank aliasing (free)
#define ADJW    32    // fixed-width adjacency (mean degree 4; P(deg>=32) ~ 0, guarded)

typedef __attribute__((ext_vector_type(8))) short s8b;
typedef __attribute__((ext_vector_type(4))) float f32x4;

__device__ __forceinline__ float us2f(unsigned short s) {
    unsigned int u = ((unsigned int)s) << 16;
    float f; __builtin_memcpy(&f, &u, 4); return f;
}
__device__ __forceinline__ unsigned short f2us(float f) {
    __hip_bfloat16 h = __float2bfloat16(f);
    unsigned short s; __builtin_memcpy(&s, &h, 2); return s;
}
__device__ __forceinline__ void acc8(float* a, uint4 v) {
    unsigned short w[8]; __builtin_memcpy(w, &v, 16);
#pragma unroll
    for (int j = 0; j < 8; j++) a[j] += us2f(w[j]);
}

// MFMA over MT*16 rows staged in xs with weight chunk WC, accumulate
template<int MT>
__device__ __forceinline__ void mfma_chunk_acc(const unsigned short* xs,
        const unsigned short* __restrict__ Wpk, int WC, f32x4 (*acc)[2], int tid) {
    int wv = tid >> 6, lane = tid & 63, quad = lane >> 4, l15 = lane & 15;
#pragma unroll
    for (int ks = 0; ks < 4; ks++) {
        const unsigned short* wb = Wpk + ((WC * 4 + ks) * 4 + quad) * 1024 + (wv * 32 + l15) * 8;
        s8b b0 = *reinterpret_cast<const s8b*>(wb);
        s8b b1 = *reinterpret_cast<const s8b*>(wb + 128);
#pragma unroll
        for (int mt = 0; mt < MT; mt++) {
            s8b afr = *reinterpret_cast<const s8b*>(&xs[(mt*16 + l15) * PITCH + ks*32 + quad*8]);
            acc[mt][0] = __builtin_amdgcn_mfma_f32_16x16x32_bf16(afr, b0, acc[mt][0], 0, 0, 0);
            acc[mt][1] = __builtin_amdgcn_mfma_f32_16x16x32_bf16(afr, b1, acc[mt][1], 0, 0, 0);
        }
    }
}

// one MFMA chunk over xs; store C rows bf16 (fresh acc)
template<int MT>
__device__ __forceinline__ void mfma_store(const unsigned short* xs,
        const unsigned short* __restrict__ Wpk, int wc,
        unsigned short* __restrict__ out, int row0, int tid) {
    int wv = tid >> 6, lane = tid & 63, quad = lane >> 4, l15 = lane & 15;
    f32x4 acc[MT][2];
#pragma unroll
    for (int mt = 0; mt < MT; mt++) {
        acc[mt][0] = (f32x4){0.f,0.f,0.f,0.f};
        acc[mt][1] = (f32x4){0.f,0.f,0.f,0.f};
    }
    mfma_chunk_acc<MT>(xs, Wpk, wc, acc, tid);
#pragma unroll
    for (int mt = 0; mt < MT; mt++)
#pragma unroll
        for (int r = 0; r < 4; r++) {
            int row = row0 + mt*16 + quad*4 + r;
#pragma unroll
            for (int nt = 0; nt < 2; nt++) {
                int col = wv*32 + nt*16 + l15;
                out[(size_t)row * DD + col] = f2us(acc[mt][nt][r]);
            }
        }
}

// ---------------- one-time prep ----------------

__device__ __forceinline__ void pack_one(const float* W, unsigned short* Wpk, int idx) {
    int k = idx >> 7, n = idx & 127;
    int c = k >> 7, ks = (k >> 5) & 3, quad = (k >> 3) & 3, j = k & 7;
    Wpk[(((c * 4 + ks) * 4 + quad) * 128 + n) * 8 + j] = f2us(W[k * 128 + n]);
}
__global__ void k_pack2(const float* __restrict__ We, const float* __restrict__ Wv,
                        unsigned short* __restrict__ WeP, unsigned short* __restrict__ WvP,
                        int* __restrict__ deg) {
    int idx = blockIdx.x * 256 + threadIdx.x;
    if (idx < N_ATOMS) deg[idx] = 0;
    const int NE = 640 * 128;
    if (idx < NE) pack_one(We, WeP, idx);
    else if (idx < NE + 512 * 128) pack_one(Wv, WvP, idx - NE);
}

__global__ void k_fill_fw(const int* __restrict__ bsrc, const int* __restrict__ bdst,
                          int* __restrict__ deg, int* __restrict__ adj) {
    int e = blockIdx.x * 256 + threadIdx.x;
    int s = bsrc[e], d = bdst[e];
    int p = atomicAdd(&deg[s], 1);
    if (p < ADJW) adj[(size_t)s * ADJW + p] = e;
    int q = atomicAdd(&deg[d], 1);
    if (q < ADJW) adj[(size_t)d * ADJW + q] = e;
}

__global__ void k_molptr2(const int* __restrict__ bmol, const int* __restrict__ amol,
                          int* __restrict__ bptr, int* __restrict__ aptr) {
    int m = threadIdx.x;
    if (m > N_MOLS) return;
    const int* ids = blockIdx.x ? amol : bmol;
    int rows = blockIdx.x ? N_ATOMS : N_BONDS;
    int* out = blockIdx.x ? aptr : bptr;
    int lo = 0, hi = rows;
    while (lo < hi) {
        int mid = (lo + hi) >> 1;
        if (ids[mid] < m) lo = mid + 1; else hi = mid;
    }
    out[m] = lo;
}

// ---------------- init (128-row tiles, not in hot loop) ----------------

__global__ __launch_bounds__(256) void k_nodes_f(
        const float* __restrict__ atoms, const float* __restrict__ Wfv,
        const float* __restrict__ bfv,
        const unsigned short* __restrict__ WvP, const unsigned short* __restrict__ WeP,
        unsigned short* __restrict__ hv, unsigned short* __restrict__ yv0,
        unsigned short* __restrict__ Zs, unsigned short* __restrict__ Zd,
        float* __restrict__ node_sum) {
    __shared__ __align__(16) unsigned short xs[128 * PITCH];
    int tid = threadIdx.x;
    int gid = blockIdx.x * 256 + tid;
    if (gid < N_MOLS * DD) node_sum[gid] = 0.f;
    int n0 = blockIdx.x * 128;
    for (int t = 0; t < 8; t++) {
        int u = tid + t * 256;
        int i = u >> 4, g = (u & 15) * 8;
        int row = n0 + i;
        float a[D_IN];
#pragma unroll
        for (int k = 0; k < D_IN; k++) a[k] = atoms[(size_t)row * D_IN + k];
        unsigned short tmp[8];
#pragma unroll
        for (int j = 0; j < 8; j++) {
            float acc1 = bfv[g + j];
#pragma unroll
            for (int k = 0; k < D_IN; k++)
                acc1 = fmaf(a[k], Wfv[k*DD + g + j], acc1);
            tmp[j] = f2us(fmaxf(acc1, 0.f));
        }
        uint4 val; __builtin_memcpy(&val, tmp, 16);
        *reinterpret_cast<uint4*>(&xs[i * PITCH + g]) = val;
        *reinterpret_cast<uint4*>(hv + (size_t)row * DD + g) = val;
    }
    __syncthreads();
    mfma_store<8>(xs, WvP, 1, yv0, n0, tid);
    mfma_store<8>(xs, WeP, 2, Zs, n0, tid);
    mfma_store<8>(xs, WeP, 3, Zd, n0, tid);
}

__global__ __launch_bounds__(256) void k_molsum_s(const unsigned short* __restrict__ x,
                                                  const int* __restrict__ mptr,
                                                  float* __restrict__ out, int S) {
    __shared__ float red[16 * 128];
    int m = blockIdx.x / S, s = blockIdx.x - m * S;
    int b = mptr[m], e = mptr[m + 1];
    int len = (e - b + S - 1) / S;
    int r0 = b + s * len;
    int r1 = min(r0 + len, e);
    int rl = threadIdx.x >> 4, g = threadIdx.x & 15;
    float acc[8] = {0,0,0,0,0,0,0,0};
    for (int r = r0 + rl; r < r1; r += 16)
        acc8(acc, *reinterpret_cast<const uint4*>(x + (size_t)r * DD + g * 8));
#pragma unroll
    for (int j = 0; j < 8; j++) red[rl * 128 + g * 8 + j] = acc[j];
    __syncthreads();
    if (threadIdx.x < 128) {
        int col = threadIdx.x;
        float sum = 0.f;
#pragma unroll
        for (int i = 0; i < 16; i++) sum += red[i * 128 + col];
        atomicAdd(&out[(size_t)m * DD + col], sum);
    }
}

__global__ __launch_bounds__(256) void k_mol_init_f(
        const float* __restrict__ ns, const float* __restrict__ Wfu,
        const float* __restrict__ bfu,
        const float* __restrict__ We, const float* __restrict__ be,
        const float* __restrict__ Wv, const float* __restrict__ bv,
        float* __restrict__ hu0, float* __restrict__ yue, float* __restrict__ yuv,
        float* __restrict__ ebar, float* __restrict__ vbar) {
    __shared__ float hrow[2 * DD];
    int tid = threadIdx.x;
    int ml = tid >> 7, d = tid & 127;
    int m = blockIdx.x * 2 + ml;
    ebar[m*DD + d] = 0.f;
    vbar[m*DD + d] = 0.f;
    float acc = bfu[d];
    for (int k = 0; k < DD; k++)
        acc = fmaf(ns[m*DD + k], Wfu[k*DD + d], acc);
    float v = fmaxf(acc, 0.f);
    hu0[m*DD + d] = v;
    hrow[ml*DD + d] = v;
    __syncthreads();
    float ae = be[d], av = bv[d];
    for (int k = 0; k < DD; k++) {
        float h = hrow[ml*DD + k];
        ae = fmaf(h, We[(512 + k)*DD + d], ae);
        av = fmaf(h, Wv[(384 + k)*DD + d], av);
    }
    yue[m*DD + d] = ae;
    yuv[m*DD + d] = av;
}

// ---------------- phi_e (32-row tiles, MT=2) ----------------

__device__ __forceinline__ void phi_e_tail2(
        unsigned short* __restrict__ he, unsigned short* xs,
        const unsigned short* __restrict__ Zs, const unsigned short* __restrict__ Zd,
        const float* __restrict__ yue,
        const int* ssrc, const int* sdst, const int* smol,
        float* __restrict__ ebar, f32x4 (*acc)[2], int e0, int tid) {
    int wv = tid >> 6, lane = tid & 63, quad = lane >> 4, l15 = lane & 15;
    for (int t = 0; t < 2; t++) {
        int u = tid + t * 256;
        int i = u >> 4, g = (u & 15) * 8;
        float s[8] = {0,0,0,0,0,0,0,0};
        acc8(s, *reinterpret_cast<const uint4*>(Zs + (size_t)ssrc[i] * DD + g));
        acc8(s, *reinterpret_cast<const uint4*>(Zd + (size_t)sdst[i] * DD + g));
        const float* yr = yue + (size_t)smol[i] * DD + g;
        float4 y0 = *reinterpret_cast<const float4*>(yr);
        float4 y1 = *reinterpret_cast<const float4*>(yr + 4);
        s[0] += y0.x; s[1] += y0.y; s[2] += y0.z; s[3] += y0.w;
        s[4] += y1.x; s[5] += y1.y; s[6] += y1.z; s[7] += y1.w;
        unsigned short tmp[8];
#pragma unroll
        for (int j = 0; j < 8; j++) tmp[j] = f2us(s[j]);
        uint4 val; __builtin_memcpy(&val, tmp, 16);
        *reinterpret_cast<uint4*>(&xs[i * PITCH + g]) = val;
    }
    __syncthreads();
#pragma unroll
    for (int nt = 0; nt < 2; nt++) {
        int col = wv*32 + nt*16 + l15;
        float run = 0.f;
        int cur = smol[quad * 4];
#pragma unroll
        for (int mt = 0; mt < 2; mt++)
#pragma unroll
            for (int r = 0; r < 4; r++) {
                int rl = mt*16 + quad*4 + r;
                float v = fmaxf(acc[mt][nt][r] + us2f(xs[rl * PITCH + col]), 0.f);
                he[(size_t)(e0 + rl) * DD + col] = f2us(v);
                int m = smol[rl];
                if (m != cur) { atomicAdd(&ebar[(size_t)cur * DD + col], run); run = 0.f; cur = m; }
                run += v;
            }
        atomicAdd(&ebar[(size_t)cur * DD + col], run);
    }
}

// round 0: he0 recomputed once, both chunks; no he read
__global__ __launch_bounds__(256) void k_phi_e_r0(
        unsigned short* __restrict__ he,
        const float* __restrict__ bo, const float* __restrict__ Wfe,
        const float* __restrict__ bfe,
        const unsigned short* __restrict__ Zs, const unsigned short* __restrict__ Zd,
        const unsigned short* __restrict__ Wpk, const float* __restrict__ yue,
        const int* __restrict__ bsrc, const int* __restrict__ bdst,
        const int* __restrict__ bmol, float* __restrict__ ebar) {
    __shared__ __align__(16) unsigned short xs[32 * PITCH];
    __shared__ int ssrc[32], sdst[32], smol[32];
    __shared__ float sbo[32];
    int tid = threadIdx.x;
    int e0 = blockIdx.x * 32;
    if (tid < 32) {
        ssrc[tid] = bsrc[e0 + tid];
        sdst[tid] = bdst[e0 + tid];
        smol[tid] = bmol[e0 + tid];
        sbo[tid]  = bo[e0 + tid];
    }
    f32x4 acc[2][2];
#pragma unroll
    for (int mt = 0; mt < 2; mt++) {
        acc[mt][0] = (f32x4){0.f,0.f,0.f,0.f};
        acc[mt][1] = (f32x4){0.f,0.f,0.f,0.f};
    }
    __syncthreads();
    for (int t = 0; t < 2; t++) {
        int u = tid + t * 256;
        int i = u >> 4, g = (u & 15) * 8;
        float b = sbo[i];
        unsigned short tmp[8];
#pragma unroll
        for (int j = 0; j < 8; j++)
            tmp[j] = f2us(fmaxf(fmaf(b, Wfe[g + j], bfe[g + j]), 0.f));
        uint4 val; __builtin_memcpy(&val, tmp, 16);
        *reinterpret_cast<uint4*>(&xs[i * PITCH + g]) = val;
    }
    __syncthreads();
    mfma_chunk_acc<2>(xs, Wpk, 0, acc, tid);
    mfma_chunk_acc<2>(xs, Wpk, 1, acc, tid);
    __syncthreads();
    phi_e_tail2(he, xs, Zs, Zd, yue, ssrc, sdst, smol, ebar, acc, e0, tid);
}

// rounds 1+
__global__ __launch_bounds__(256) void k_phi_e_n(
        unsigned short* __restrict__ he,
        const float* __restrict__ bo, const float* __restrict__ Wfe,
        const float* __restrict__ bfe,
        const unsigned short* __restrict__ Zs, const unsigned short* __restrict__ Zd,
        const unsigned short* __restrict__ Wpk, const float* __restrict__ yue,
        const int* __restrict__ bsrc, const int* __restrict__ bdst,
        const int* __restrict__ bmol, float* __restrict__ ebar) {
    __shared__ __align__(16) unsigned short xs[32 * PITCH];
    __shared__ int ssrc[32], sdst[32], smol[32];
    __shared__ float sbo[32];
    int tid = threadIdx.x;
    int e0 = blockIdx.x * 32;
    if (tid < 32) {
        ssrc[tid] = bsrc[e0 + tid];
        sdst[tid] = bdst[e0 + tid];
        smol[tid] = bmol[e0 + tid];
        sbo[tid]  = bo[e0 + tid];
    }
    f32x4 acc[2][2];
#pragma unroll
    for (int mt = 0; mt < 2; mt++) {
        acc[mt][0] = (f32x4){0.f,0.f,0.f,0.f};
        acc[mt][1] = (f32x4){0.f,0.f,0.f,0.f};
    }
    // chunk 0: he rows
    for (int t = 0; t < 2; t++) {
        int u = tid + t * 256;
        int i = u >> 4, g = (u & 15) * 8;
        *reinterpret_cast<uint4*>(&xs[i * PITCH + g]) =
            *reinterpret_cast<const uint4*>(he + (size_t)(e0 + i) * DD + g);
    }
    __syncthreads();
    mfma_chunk_acc<2>(xs, Wpk, 0, acc, tid);
    __syncthreads();
    // chunk 1: he0 recomputed rank-1
    for (int t = 0; t < 2; t++) {
        int u = tid + t * 256;
        int i = u >> 4, g = (u & 15) * 8;
        float b = sbo[i];
        unsigned short tmp[8];
#pragma unroll
        for (int j = 0; j < 8; j++)
            tmp[j] = f2us(fmaxf(fmaf(b, Wfe[g + j], bfe[g + j]), 0.f));
        uint4 val; __builtin_memcpy(&val, tmp, 16);
        *reinterpret_cast<uint4*>(&xs[i * PITCH + g]) = val;
    }
    __syncthreads();
    mfma_chunk_acc<2>(xs, Wpk, 1, acc, tid);
    __syncthreads();
    phi_e_tail2(he, xs, Zs, Zd, yue, ssrc, sdst, smol, ebar, acc, e0, tid);
}

// ---------------- e_bar_i gather (fixed-width adjacency) ----------------
__global__ __launch_bounds__(256) void k_ebar(const unsigned short* __restrict__ he,
                                              const int* __restrict__ deg,
                                              const int* __restrict__ adj,
                                              unsigned short* __restrict__ ebar_i) {
    int n = blockIdx.x * 16 + (threadIdx.x >> 4);
    int g = threadIdx.x & 15;
    int dn = min(deg[n], ADJW);
    const int* ap = adj + (size_t)n * ADJW;
    float acc[8] = {0,0,0,0,0,0,0,0};
    int j = 0;
    for (; j + 3 < dn; j += 4) {
        uint4 v0 = *reinterpret_cast<const uint4*>(he + (size_t)ap[j]     * DD + g * 8);
        uint4 v1 = *reinterpret_cast<const uint4*>(he + (size_t)ap[j + 1] * DD + g * 8);
        uint4 v2 = *reinterpret_cast<const uint4*>(he + (size_t)ap[j + 2] * DD + g * 8);
        uint4 v3 = *reinterpret_cast<const uint4*>(he + (size_t)ap[j + 3] * DD + g * 8);
        acc8(acc, v0); acc8(acc, v1); acc8(acc, v2); acc8(acc, v3);
    }
    for (; j < dn; j++)
        acc8(acc, *reinterpret_cast<const uint4*>(he + (size_t)ap[j] * DD + g * 8));
    unsigned short o[8];
#pragma unroll
    for (int k = 0; k < 8; k++) o[k] = f2us(acc[k]);
    uint4 ov; __builtin_memcpy(&ov, o, 16);
    *reinterpret_cast<uint4*>(ebar_i + (size_t)n * DD + g * 8) = ov;
}

// ---------------- phi_v (64-row tiles, MT=4) ----------------
__global__ __launch_bounds__(256) void k_phi_v(
        unsigned short* __restrict__ hv, const unsigned short* __restrict__ ebar_i,
        const unsigned short* __restrict__ yv0,
        const unsigned short* __restrict__ WvP, const unsigned short* __restrict__ WeP,
        const float* __restrict__ yuv, const int* __restrict__ amol,
        float* __restrict__ vbar,
        unsigned short* __restrict__ Zs, unsigned short* __restrict__ Zd, int do_z) {
    __shared__ __align__(16) unsigned short xs[64 * PITCH];
    __shared__ int smol[64];
    int tid = threadIdx.x;
    int n0 = blockIdx.x * 64;
    if (tid < 64) smol[tid] = amol[n0 + tid];
    int wv = tid >> 6, lane = tid & 63, quad = lane >> 4, l15 = lane & 15;
    f32x4 acc[4][2];
#pragma unroll
    for (int mt = 0; mt < 4; mt++) {
        acc[mt][0] = (f32x4){0.f,0.f,0.f,0.f};
        acc[mt][1] = (f32x4){0.f,0.f,0.f,0.f};
    }
    const unsigned short* bases[2] = { hv + (size_t)n0 * DD, ebar_i + (size_t)n0 * DD };
    const int wcs[2] = {0, 2};
    for (int c = 0; c < 2; c++) {
        if (c) __syncthreads();
        for (int t = 0; t < 4; t++) {
            int u = tid + t * 256;
            int i = u >> 4, g = (u & 15) * 8;
            *reinterpret_cast<uint4*>(&xs[i * PITCH + g]) =
                *reinterpret_cast<const uint4*>(bases[c] + (size_t)i * DD + g);
        }
        __syncthreads();
        mfma_chunk_acc<4>(xs, WvP, wcs[c], acc, tid);
    }
    __syncthreads();
    for (int t = 0; t < 4; t++) {
        int u = tid + t * 256;
        int i = u >> 4, g = (u & 15) * 8;
        float s[8] = {0,0,0,0,0,0,0,0};
        acc8(s, *reinterpret_cast<const uint4*>(yv0 + (size_t)(n0 + i) * DD + g));
        const float* yr = yuv + (size_t)smol[i] * DD + g;
        float4 y0 = *reinterpret_cast<const float4*>(yr);
        float4 y1 = *reinterpret_cast<const float4*>(yr + 4);
        s[0] += y0.x; s[1] += y0.y; s[2] += y0.z; s[3] += y0.w;
        s[4] += y1.x; s[5] += y1.y; s[6] += y1.z; s[7] += y1.w;
        unsigned short tmp[8];
#pragma unroll
        for (int j = 0; j < 8; j++) tmp[j] = f2us(s[j]);
        uint4 val; __builtin_memcpy(&val, tmp, 16);
        *reinterpret_cast<uint4*>(&xs[i * PITCH + g]) = val;
    }
    __syncthreads();
#pragma unroll
    for (int nt = 0; nt < 2; nt++) {
        int col = wv*32 + nt*16 + l15;
        float run = 0.f;
        int cur = smol[quad * 4];
#pragma unroll
        for (int mt = 0; mt < 4; mt++)
#pragma unroll
            for (int r = 0; r < 4; r++) {
                int rl = mt*16 + quad*4 + r;
                float v = fmaxf(acc[mt][nt][r] + us2f(xs[rl * PITCH + col]), 0.f);
                unsigned short vb = f2us(v);
                hv[(size_t)(n0 + rl) * DD + col] = vb;
                xs[rl * PITCH + col] = vb;   // per-thread RMW, race-free
                int m = smol[rl];
                if (m != cur) { atomicAdd(&vbar[(size_t)cur * DD + col], run); run = 0.f; cur = m; }
                run += v;
            }
        atomicAdd(&vbar[(size_t)cur * DD + col], run);
    }
    if (do_z) {
        __syncthreads();
        mfma_store<4>(xs, WeP, 2, Zs, n0, tid);
        mfma_store<4>(xs, WeP, 3, Zd, n0, tid);
    }
}

// ---------------- phi_u fused: next-round yue/yuv + zero ebar/vbar ----------------
__global__ __launch_bounds__(256) void k_phi_u_f(
        const float* __restrict__ hu_in, const float* __restrict__ hu0,
        float* __restrict__ ebar, float* __restrict__ vbar,
        const float* __restrict__ Wu, const float* __restrict__ bu,
        const float* __restrict__ We, const float* __restrict__ be,
        const float* __restrict__ Wv, const float* __restrict__ bv,
        float* __restrict__ hu_out, float* __restrict__ dout,
        float* __restrict__ yue, float* __restrict__ yuv) {
    __shared__ float hrow[2 * DD];
    int tid = threadIdx.x;
    int ml = tid >> 7, d = tid & 127;
    int m = blockIdx.x * 2 + ml;
    float acc = bu[d];
    const float* segs[4] = { hu_in + m*DD, hu0 + m*DD, ebar + m*DD, vbar + m*DD };
    for (int s = 0; s < 4; s++) {
        const float* x = segs[s];
        const float* W = Wu + (s*DD)*DD + d;
        for (int k = 0; k < DD; k++)
            acc = fmaf(x[k], W[k*DD], acc);
    }
    float v = fmaxf(acc, 0.f);
    hu_out[m*DD + d] = v;
    dout[m*DD + d] = v;
    hrow[ml*DD + d] = v;
    __syncthreads();
    ebar[m*DD + d] = 0.f;
    vbar[m*DD + d] = 0.f;
    float ae = be[d], av = bv[d];
    for (int k = 0; k < DD; k++) {
        float h = hrow[ml*DD + k];
        ae = fmaf(h, We[(512 + k)*DD + d], ae);
        av = fmaf(h, Wv[(384 + k)*DD + d], av);
    }
    yue[m*DD + d] = ae;
    yuv[m*DD + d] = av;
}

// ---------------- launch ----------------

extern "C" void kernel_launch(void* const* d_in, const int* in_sizes, int n_in,
                              void* d_out, int out_size, void* d_ws, size_t ws_size,
                              hipStream_t stream) {
    const float* atoms = (const float*)d_in[0];
    const float* bo    = (const float*)d_in[1];
    const float* Wfe   = (const float*)d_in[2];
    const float* bfe   = (const float*)d_in[3];
    const float* Wfv   = (const float*)d_in[4];
    const float* bfv   = (const float*)d_in[5];
    const float* Wfu   = (const float*)d_in[6];
    const float* bfu   = (const float*)d_in[7];
    const float* We    = (const float*)d_in[8];
    const float* be    = (const float*)d_in[9];
    const float* Wv    = (const float*)d_in[10];
    const float* bv    = (const float*)d_in[11];
    const float* Wu    = (const float*)d_in[12];
    const float* bu    = (const float*)d_in[13];
    const int* bsrc    = (const int*)d_in[14];
    const int* bdst    = (const int*)d_in[15];
    const int* amol    = (const int*)d_in[16];
    const int* bmol    = (const int*)d_in[17];

    char* p = (char*)d_ws;
    auto alloc = [&](size_t bytes) {
        char* r = p;
        p += (bytes + 255) & ~(size_t)255;
        return r;
    };
    unsigned short* he     = (unsigned short*)alloc((size_t)N_BONDS * DD * 2);
    unsigned short* hv     = (unsigned short*)alloc((size_t)N_ATOMS * DD * 2);
    unsigned short* yv0    = (unsigned short*)alloc((size_t)N_ATOMS * DD * 2);
    unsigned short* Zs     = (unsigned short*)alloc((size_t)N_ATOMS * DD * 2);
    unsigned short* Zd     = (unsigned short*)alloc((size_t)N_ATOMS * DD * 2);
    unsigned short* ebar_i = (unsigned short*)alloc((size_t)N_ATOMS * DD * 2);
    unsigned short* WeP    = (unsigned short*)alloc((size_t)640 * DD * 2);
    unsigned short* WvP    = (unsigned short*)alloc((size_t)512 * DD * 2);
    int* deg      = (int*)alloc((size_t)N_ATOMS * 4);
    int* adj      = (int*)alloc((size_t)N_ATOMS * ADJW * 4);
    int* bmol_ptr = (int*)alloc((size_t)(N_MOLS + 1) * 4);
    int* amol_ptr = (int*)alloc((size_t)(N_MOLS + 1) * 4);
    float* node_sum = (float*)alloc((size_t)N_MOLS * DD * 4);
    float* hu0   = (float*)alloc((size_t)N_MOLS * DD * 4);
    float* huA   = (float*)alloc((size_t)N_MOLS * DD * 4);
    float* huB   = (float*)alloc((size_t)N_MOLS * DD * 4);
    float* ebar  = (float*)alloc((size_t)N_MOLS * DD * 4);
    float* vbar  = (float*)alloc((size_t)N_MOLS * DD * 4);
    float* yue   = (float*)alloc((size_t)N_MOLS * DD * 4);
    float* yuv   = (float*)alloc((size_t)N_MOLS * DD * 4);

    // ---- prep ----
    k_pack2<<<(640*DD + 512*DD)/256, 256, 0, stream>>>(We, Wv, WeP, WvP, deg);
    k_fill_fw<<<N_BONDS/256, 256, 0, stream>>>(bsrc, bdst, deg, adj);
    k_molptr2<<<2, 1024, 0, stream>>>(bmol, amol, bmol_ptr, amol_ptr);

    // ---- init ----
    k_nodes_f<<<N_ATOMS/128, 256, 0, stream>>>(atoms, Wfv, bfv, WvP, WeP,
                                               hv, yv0, Zs, Zd, node_sum);
    k_molsum_s<<<N_MOLS*2, 256, 0, stream>>>(hv, amol_ptr, node_sum, 2);
    k_mol_init_f<<<N_MOLS/2, 256, 0, stream>>>(node_sum, Wfu, bfu, We, be, Wv, bv,
                                               hu0, yue, yuv, ebar, vbar);

    const float* hu_in = hu0; float* hu_out = huA;

    for (int r = 0; r < REPEAT; r++) {
        if (r == 0)
            k_phi_e_r0<<<N_BONDS/32, 256, 0, stream>>>(he, bo, Wfe, bfe, Zs, Zd, WeP,
                                                       yue, bsrc, bdst, bmol, ebar);
        else
            k_phi_e_n<<<N_BONDS/32, 256, 0, stream>>>(he, bo, Wfe, bfe, Zs, Zd, WeP,
                                                      yue, bsrc, bdst, bmol, ebar);
        k_ebar<<<N_ATOMS/16, 256, 0, stream>>>(he, deg, adj, ebar_i);
        k_phi_v<<<N_ATOMS/64, 256, 0, stream>>>(hv, ebar_i, yv0, WvP, WeP, yuv,
                                                amol, vbar, Zs, Zd, (r < REPEAT - 1) ? 1 : 0);
        k_phi_u_f<<<N_MOLS/2, 256, 0, stream>>>(hu_in, hu0, ebar, vbar, Wu, bu,
                                                We, be, Wv, bv,
                                                hu_out, (float*)d_out, yue, yuv);
        hu_in = hu_out; hu_out = (hu_out == huA) ? huB : huA;
    }
}

// Round 17
// 435.835 us; speedup vs baseline: 1.0552x; 1.0552x over previous
//
#include <hip/hip_runtime.h>
#include <hip/hip_bf16.h>
#include <stdint.h>

#define N_ATOMS 65536
#define N_BONDS 131072
#define N_MOLS  512
#define D_IN    16
#define DD      128
#define REPEAT  3
#define PITCH   136   // LDS row pitch (bf16): 2-way max bank aliasing (free)
#define ADJW    32    // fixed-width adjacency (mean degree 4; P(deg>=32) ~ 0, guarded)

typedef __attribute__((ext_vector_type(8))) short s8b;
typedef __attribute__((ext_vector_type(4))) float f32x4;

__device__ __forceinline__ float us2f(unsigned short s) {
    unsigned int u = ((unsigned int)s) << 16;
    float f; __builtin_memcpy(&f, &u, 4); return f;
}
__device__ __forceinline__ unsigned short f2us(float f) {
    __hip_bfloat16 h = __float2bfloat16(f);
    unsigned short s; __builtin_memcpy(&s, &h, 2); return s;
}
__device__ __forceinline__ void acc8(float* a, uint4 v) {
    unsigned short w[8]; __builtin_memcpy(w, &v, 16);
#pragma unroll
    for (int j = 0; j < 8; j++) a[j] += us2f(w[j]);
}

// MFMA over MT*16 rows staged in xs with weight chunk WC, accumulate
template<int MT>
__device__ __forceinline__ void mfma_chunk_acc(const unsigned short* xs,
        const unsigned short* __restrict__ Wpk, int WC, f32x4 (*acc)[2], int tid) {
    int wv = tid >> 6, lane = tid & 63, quad = lane >> 4, l15 = lane & 15;
#pragma unroll
    for (int ks = 0; ks < 4; ks++) {
        const unsigned short* wb = Wpk + ((WC * 4 + ks) * 4 + quad) * 1024 + (wv * 32 + l15) * 8;
        s8b b0 = *reinterpret_cast<const s8b*>(wb);
        s8b b1 = *reinterpret_cast<const s8b*>(wb + 128);
#pragma unroll
        for (int mt = 0; mt < MT; mt++) {
            s8b afr = *reinterpret_cast<const s8b*>(&xs[(mt*16 + l15) * PITCH + ks*32 + quad*8]);
            acc[mt][0] = __builtin_amdgcn_mfma_f32_16x16x32_bf16(afr, b0, acc[mt][0], 0, 0, 0);
            acc[mt][1] = __builtin_amdgcn_mfma_f32_16x16x32_bf16(afr, b1, acc[mt][1], 0, 0, 0);
        }
    }
}

// one MFMA chunk over xs; store C rows bf16 (fresh acc)
template<int MT>
__device__ __forceinline__ void mfma_store(const unsigned short* xs,
        const unsigned short* __restrict__ Wpk, int wc,
        unsigned short* __restrict__ out, int row0, int tid) {
    int wv = tid >> 6, lane = tid & 63, quad = lane >> 4, l15 = lane & 15;
    f32x4 acc[MT][2];
#pragma unroll
    for (int mt = 0; mt < MT; mt++) {
        acc[mt][0] = (f32x4){0.f,0.f,0.f,0.f};
        acc[mt][1] = (f32x4){0.f,0.f,0.f,0.f};
    }
    mfma_chunk_acc<MT>(xs, Wpk, wc, acc, tid);
#pragma unroll
    for (int mt = 0; mt < MT; mt++)
#pragma unroll
        for (int r = 0; r < 4; r++) {
            int row = row0 + mt*16 + quad*4 + r;
#pragma unroll
            for (int nt = 0; nt < 2; nt++) {
                int col = wv*32 + nt*16 + l15;
                out[(size_t)row * DD + col] = f2us(acc[mt][nt][r]);
            }
        }
}

// ---------------- one-time prep ----------------

__device__ __forceinline__ void pack_one(const float* W, unsigned short* Wpk, int idx) {
    int k = idx >> 7, n = idx & 127;
    int c = k >> 7, ks = (k >> 5) & 3, quad = (k >> 3) & 3, j = k & 7;
    Wpk[(((c * 4 + ks) * 4 + quad) * 128 + n) * 8 + j] = f2us(W[k * 128 + n]);
}
__global__ void k_pack2(const float* __restrict__ We, const float* __restrict__ Wv,
                        unsigned short* __restrict__ WeP, unsigned short* __restrict__ WvP,
                        int* __restrict__ deg) {
    int idx = blockIdx.x * 256 + threadIdx.x;
    if (idx < N_ATOMS) deg[idx] = 0;
    const int NE = 640 * 128;
    if (idx < NE) pack_one(We, WeP, idx);
    else if (idx < NE + 512 * 128) pack_one(Wv, WvP, idx - NE);
}

__global__ void k_fill_fw(const int* __restrict__ bsrc, const int* __restrict__ bdst,
                          int* __restrict__ deg, int* __restrict__ adj) {
    int e = blockIdx.x * 256 + threadIdx.x;
    int s = bsrc[e], d = bdst[e];
    int p = atomicAdd(&deg[s], 1);
    if (p < ADJW) adj[(size_t)s * ADJW + p] = e;
    int q = atomicAdd(&deg[d], 1);
    if (q < ADJW) adj[(size_t)d * ADJW + q] = e;
}

__global__ void k_molptr2(const int* __restrict__ bmol, const int* __restrict__ amol,
                          int* __restrict__ bptr, int* __restrict__ aptr) {
    int m = threadIdx.x;
    if (m > N_MOLS) return;
    const int* ids = blockIdx.x ? amol : bmol;
    int rows = blockIdx.x ? N_ATOMS : N_BONDS;
    int* out = blockIdx.x ? aptr : bptr;
    int lo = 0, hi = rows;
    while (lo < hi) {
        int mid = (lo + hi) >> 1;
        if (ids[mid] < m) lo = mid + 1; else hi = mid;
    }
    out[m] = lo;
}

// ---------------- init (128-row tiles, not in hot loop) ----------------

__global__ __launch_bounds__(256) void k_nodes_f(
        const float* __restrict__ atoms, const float* __restrict__ Wfv,
        const float* __restrict__ bfv,
        const unsigned short* __restrict__ WvP, const unsigned short* __restrict__ WeP,
        unsigned short* __restrict__ hv, unsigned short* __restrict__ yv0,
        unsigned short* __restrict__ Zs, unsigned short* __restrict__ Zd,
        float* __restrict__ node_sum) {
    __shared__ __align__(16) unsigned short xs[128 * PITCH];
    int tid = threadIdx.x;
    int gid = blockIdx.x * 256 + tid;
    if (gid < N_MOLS * DD) node_sum[gid] = 0.f;
    int n0 = blockIdx.x * 128;
    for (int t = 0; t < 8; t++) {
        int u = tid + t * 256;
        int i = u >> 4, g = (u & 15) * 8;
        int row = n0 + i;
        float a[D_IN];
#pragma unroll
        for (int k = 0; k < D_IN; k++) a[k] = atoms[(size_t)row * D_IN + k];
        unsigned short tmp[8];
#pragma unroll
        for (int j = 0; j < 8; j++) {
            float acc1 = bfv[g + j];
#pragma unroll
            for (int k = 0; k < D_IN; k++)
                acc1 = fmaf(a[k], Wfv[k*DD + g + j], acc1);
            tmp[j] = f2us(fmaxf(acc1, 0.f));
        }
        uint4 val; __builtin_memcpy(&val, tmp, 16);
        *reinterpret_cast<uint4*>(&xs[i * PITCH + g]) = val;
        *reinterpret_cast<uint4*>(hv + (size_t)row * DD + g) = val;
    }
    __syncthreads();
    mfma_store<8>(xs, WvP, 1, yv0, n0, tid);
    mfma_store<8>(xs, WeP, 2, Zs, n0, tid);
    mfma_store<8>(xs, WeP, 3, Zd, n0, tid);
}

__global__ __launch_bounds__(256) void k_molsum_s(const unsigned short* __restrict__ x,
                                                  const int* __restrict__ mptr,
                                                  float* __restrict__ out, int S) {
    __shared__ float red[16 * 128];
    int m = blockIdx.x / S, s = blockIdx.x - m * S;
    int b = mptr[m], e = mptr[m + 1];
    int len = (e - b + S - 1) / S;
    int r0 = b + s * len;
    int r1 = min(r0 + len, e);
    int rl = threadIdx.x >> 4, g = threadIdx.x & 15;
    float acc[8] = {0,0,0,0,0,0,0,0};
    for (int r = r0 + rl; r < r1; r += 16)
        acc8(acc, *reinterpret_cast<const uint4*>(x + (size_t)r * DD + g * 8));
#pragma unroll
    for (int j = 0; j < 8; j++) red[rl * 128 + g * 8 + j] = acc[j];
    __syncthreads();
    if (threadIdx.x < 128) {
        int col = threadIdx.x;
        float sum = 0.f;
#pragma unroll
        for (int i = 0; i < 16; i++) sum += red[i * 128 + col];
        atomicAdd(&out[(size_t)m * DD + col], sum);
    }
}

__global__ __launch_bounds__(256) void k_mol_init_f(
        const float* __restrict__ ns, const float* __restrict__ Wfu,
        const float* __restrict__ bfu,
        const float* __restrict__ We, const float* __restrict__ be,
        const float* __restrict__ Wv, const float* __restrict__ bv,
        float* __restrict__ hu0, float* __restrict__ yue, float* __restrict__ yuv,
        float* __restrict__ ebar, float* __restrict__ vbar) {
    __shared__ float hrow[2 * DD];
    int tid = threadIdx.x;
    int ml = tid >> 7, d = tid & 127;
    int m = blockIdx.x * 2 + ml;
    ebar[m*DD + d] = 0.f;
    vbar[m*DD + d] = 0.f;
    float acc = bfu[d];
    for (int k = 0; k < DD; k++)
        acc = fmaf(ns[m*DD + k], Wfu[k*DD + d], acc);
    float v = fmaxf(acc, 0.f);
    hu0[m*DD + d] = v;
    hrow[ml*DD + d] = v;
    __syncthreads();
    float ae = be[d], av = bv[d];
    for (int k = 0; k < DD; k++) {
        float h = hrow[ml*DD + k];
        ae = fmaf(h, We[(512 + k)*DD + d], ae);
        av = fmaf(h, Wv[(384 + k)*DD + d], av);
    }
    yue[m*DD + d] = ae;
    yuv[m*DD + d] = av;
}

// ---------------- phi_e (64-row tiles, MT=4) ----------------

__device__ __forceinline__ void phi_e_tail4(
        unsigned short* __restrict__ he, unsigned short* xs,
        const unsigned short* __restrict__ Zs, const unsigned short* __restrict__ Zd,
        const float* __restrict__ yue,
        const int* ssrc, const int* sdst, const int* smol,
        float* __restrict__ ebar, f32x4 (*acc)[2], int e0, int tid) {
    int wv = tid >> 6, lane = tid & 63, quad = lane >> 4, l15 = lane & 15;
    for (int t = 0; t < 4; t++) {
        int u = tid + t * 256;
        int i = u >> 4, g = (u & 15) * 8;
        float s[8] = {0,0,0,0,0,0,0,0};
        acc8(s, *reinterpret_cast<const uint4*>(Zs + (size_t)ssrc[i] * DD + g));
        acc8(s, *reinterpret_cast<const uint4*>(Zd + (size_t)sdst[i] * DD + g));
        const float* yr = yue + (size_t)smol[i] * DD + g;
        float4 y0 = *reinterpret_cast<const float4*>(yr);
        float4 y1 = *reinterpret_cast<const float4*>(yr + 4);
        s[0] += y0.x; s[1] += y0.y; s[2] += y0.z; s[3] += y0.w;
        s[4] += y1.x; s[5] += y1.y; s[6] += y1.z; s[7] += y1.w;
        unsigned short tmp[8];
#pragma unroll
        for (int j = 0; j < 8; j++) tmp[j] = f2us(s[j]);
        uint4 val; __builtin_memcpy(&val, tmp, 16);
        *reinterpret_cast<uint4*>(&xs[i * PITCH + g]) = val;
    }
    __syncthreads();
#pragma unroll
    for (int nt = 0; nt < 2; nt++) {
        int col = wv*32 + nt*16 + l15;
        float run = 0.f;
        int cur = smol[quad * 4];
#pragma unroll
        for (int mt = 0; mt < 4; mt++)
#pragma unroll
            for (int r = 0; r < 4; r++) {
                int rl = mt*16 + quad*4 + r;
                float v = fmaxf(acc[mt][nt][r] + us2f(xs[rl * PITCH + col]), 0.f);
                he[(size_t)(e0 + rl) * DD + col] = f2us(v);
                int m = smol[rl];
                if (m != cur) { atomicAdd(&ebar[(size_t)cur * DD + col], run); run = 0.f; cur = m; }
                run += v;
            }
        atomicAdd(&ebar[(size_t)cur * DD + col], run);
    }
}

// round 0: he0 recomputed once, both chunks; no he read
__global__ __launch_bounds__(256) void k_phi_e_r0(
        unsigned short* __restrict__ he,
        const float* __restrict__ bo, const float* __restrict__ Wfe,
        const float* __restrict__ bfe,
        const unsigned short* __restrict__ Zs, const unsigned short* __restrict__ Zd,
        const unsigned short* __restrict__ Wpk, const float* __restrict__ yue,
        const int* __restrict__ bsrc, const int* __restrict__ bdst,
        const int* __restrict__ bmol, float* __restrict__ ebar) {
    __shared__ __align__(16) unsigned short xs[64 * PITCH];
    __shared__ int ssrc[64], sdst[64], smol[64];
    __shared__ float sbo[64];
    int tid = threadIdx.x;
    int e0 = blockIdx.x * 64;
    if (tid < 64) {
        ssrc[tid] = bsrc[e0 + tid];
        sdst[tid] = bdst[e0 + tid];
        smol[tid] = bmol[e0 + tid];
        sbo[tid]  = bo[e0 + tid];
    }
    f32x4 acc[4][2];
#pragma unroll
    for (int mt = 0; mt < 4; mt++) {
        acc[mt][0] = (f32x4){0.f,0.f,0.f,0.f};
        acc[mt][1] = (f32x4){0.f,0.f,0.f,0.f};
    }
    __syncthreads();
    for (int t = 0; t < 4; t++) {
        int u = tid + t * 256;
        int i = u >> 4, g = (u & 15) * 8;
        float b = sbo[i];
        unsigned short tmp[8];
#pragma unroll
        for (int j = 0; j < 8; j++)
            tmp[j] = f2us(fmaxf(fmaf(b, Wfe[g + j], bfe[g + j]), 0.f));
        uint4 val; __builtin_memcpy(&val, tmp, 16);
        *reinterpret_cast<uint4*>(&xs[i * PITCH + g]) = val;
    }
    __syncthreads();
    mfma_chunk_acc<4>(xs, Wpk, 0, acc, tid);
    mfma_chunk_acc<4>(xs, Wpk, 1, acc, tid);
    __syncthreads();
    phi_e_tail4(he, xs, Zs, Zd, yue, ssrc, sdst, smol, ebar, acc, e0, tid);
}

// rounds 1+
__global__ __launch_bounds__(256) void k_phi_e_n(
        unsigned short* __restrict__ he,
        const float* __restrict__ bo, const float* __restrict__ Wfe,
        const float* __restrict__ bfe,
        const unsigned short* __restrict__ Zs, const unsigned short* __restrict__ Zd,
        const unsigned short* __restrict__ Wpk, const float* __restrict__ yue,
        const int* __restrict__ bsrc, const int* __restrict__ bdst,
        const int* __restrict__ bmol, float* __restrict__ ebar) {
    __shared__ __align__(16) unsigned short xs[64 * PITCH];
    __shared__ int ssrc[64], sdst[64], smol[64];
    __shared__ float sbo[64];
    int tid = threadIdx.x;
    int e0 = blockIdx.x * 64;
    if (tid < 64) {
        ssrc[tid] = bsrc[e0 + tid];
        sdst[tid] = bdst[e0 + tid];
        smol[tid] = bmol[e0 + tid];
        sbo[tid]  = bo[e0 + tid];
    }
    f32x4 acc[4][2];
#pragma unroll
    for (int mt = 0; mt < 4; mt++) {
        acc[mt][0] = (f32x4){0.f,0.f,0.f,0.f};
        acc[mt][1] = (f32x4){0.f,0.f,0.f,0.f};
    }
    // chunk 0: he rows
    for (int t = 0; t < 4; t++) {
        int u = tid + t * 256;
        int i = u >> 4, g = (u & 15) * 8;
        *reinterpret_cast<uint4*>(&xs[i * PITCH + g]) =
            *reinterpret_cast<const uint4*>(he + (size_t)(e0 + i) * DD + g);
    }
    __syncthreads();
    mfma_chunk_acc<4>(xs, Wpk, 0, acc, tid);
    __syncthreads();
    // chunk 1: he0 recomputed rank-1
    for (int t = 0; t < 4; t++) {
        int u = tid + t * 256;
        int i = u >> 4, g = (u & 15) * 8;
        float b = sbo[i];
        unsigned short tmp[8];
#pragma unroll
        for (int j = 0; j < 8; j++)
            tmp[j] = f2us(fmaxf(fmaf(b, Wfe[g + j], bfe[g + j]), 0.f));
        uint4 val; __builtin_memcpy(&val, tmp, 16);
        *reinterpret_cast<uint4*>(&xs[i * PITCH + g]) = val;
    }
    __syncthreads();
    mfma_chunk_acc<4>(xs, Wpk, 1, acc, tid);
    __syncthreads();
    phi_e_tail4(he, xs, Zs, Zd, yue, ssrc, sdst, smol, ebar, acc, e0, tid);
}

// ---------------- e_bar_i gather (fixed-width adjacency) ----------------
__global__ __launch_bounds__(256) void k_ebar(const unsigned short* __restrict__ he,
                                              const int* __restrict__ deg,
                                              const int* __restrict__ adj,
                                              unsigned short* __restrict__ ebar_i) {
    int n = blockIdx.x * 16 + (threadIdx.x >> 4);
    int g = threadIdx.x & 15;
    int dn = min(deg[n], ADJW);
    const int* ap = adj + (size_t)n * ADJW;
    float acc[8] = {0,0,0,0,0,0,0,0};
    int j = 0;
    for (; j + 3 < dn; j += 4) {
        uint4 v0 = *reinterpret_cast<const uint4*>(he + (size_t)ap[j]     * DD + g * 8);
        uint4 v1 = *reinterpret_cast<const uint4*>(he + (size_t)ap[j + 1] * DD + g * 8);
        uint4 v2 = *reinterpret_cast<const uint4*>(he + (size_t)ap[j + 2] * DD + g * 8);
        uint4 v3 = *reinterpret_cast<const uint4*>(he + (size_t)ap[j + 3] * DD + g * 8);
        acc8(acc, v0); acc8(acc, v1); acc8(acc, v2); acc8(acc, v3);
    }
    for (; j < dn; j++)
        acc8(acc, *reinterpret_cast<const uint4*>(he + (size_t)ap[j] * DD + g * 8));
    unsigned short o[8];
#pragma unroll
    for (int k = 0; k < 8; k++) o[k] = f2us(acc[k]);
    uint4 ov; __builtin_memcpy(&ov, o, 16);
    *reinterpret_cast<uint4*>(ebar_i + (size_t)n * DD + g * 8) = ov;
}

// ---------------- phi_v (64-row tiles, MT=4) ----------------
__global__ __launch_bounds__(256) void k_phi_v(
        unsigned short* __restrict__ hv, const unsigned short* __restrict__ ebar_i,
        const unsigned short* __restrict__ yv0,
        const unsigned short* __restrict__ WvP, const unsigned short* __restrict__ WeP,
        const float* __restrict__ yuv, const int* __restrict__ amol,
        float* __restrict__ vbar,
        unsigned short* __restrict__ Zs, unsigned short* __restrict__ Zd, int do_z) {
    __shared__ __align__(16) unsigned short xs[64 * PITCH];
    __shared__ int smol[64];
    int tid = threadIdx.x;
    int n0 = blockIdx.x * 64;
    if (tid < 64) smol[tid] = amol[n0 + tid];
    int wv = tid >> 6, lane = tid & 63, quad = lane >> 4, l15 = lane & 15;
    f32x4 acc[4][2];
#pragma unroll
    for (int mt = 0; mt < 4; mt++) {
        acc[mt][0] = (f32x4){0.f,0.f,0.f,0.f};
        acc[mt][1] = (f32x4){0.f,0.f,0.f,0.f};
    }
    const unsigned short* bases[2] = { hv + (size_t)n0 * DD, ebar_i + (size_t)n0 * DD };
    const int wcs[2] = {0, 2};
    for (int c = 0; c < 2; c++) {
        if (c) __syncthreads();
        for (int t = 0; t < 4; t++) {
            int u = tid + t * 256;
            int i = u >> 4, g = (u & 15) * 8;
            *reinterpret_cast<uint4*>(&xs[i * PITCH + g]) =
                *reinterpret_cast<const uint4*>(bases[c] + (size_t)i * DD + g);
        }
        __syncthreads();
        mfma_chunk_acc<4>(xs, WvP, wcs[c], acc, tid);
    }
    __syncthreads();
    for (int t = 0; t < 4; t++) {
        int u = tid + t * 256;
        int i = u >> 4, g = (u & 15) * 8;
        float s[8] = {0,0,0,0,0,0,0,0};
        acc8(s, *reinterpret_cast<const uint4*>(yv0 + (size_t)(n0 + i) * DD + g));
        const float* yr = yuv + (size_t)smol[i] * DD + g;
        float4 y0 = *reinterpret_cast<const float4*>(yr);
        float4 y1 = *reinterpret_cast<const float4*>(yr + 4);
        s[0] += y0.x; s[1] += y0.y; s[2] += y0.z; s[3] += y0.w;
        s[4] += y1.x; s[5] += y1.y; s[6] += y1.z; s[7] += y1.w;
        unsigned short tmp[8];
#pragma unroll
        for (int j = 0; j < 8; j++) tmp[j] = f2us(s[j]);
        uint4 val; __builtin_memcpy(&val, tmp, 16);
        *reinterpret_cast<uint4*>(&xs[i * PITCH + g]) = val;
    }
    __syncthreads();
#pragma unroll
    for (int nt = 0; nt < 2; nt++) {
        int col = wv*32 + nt*16 + l15;
        float run = 0.f;
        int cur = smol[quad * 4];
#pragma unroll
        for (int mt = 0; mt < 4; mt++)
#pragma unroll
            for (int r = 0; r < 4; r++) {
                int rl = mt*16 + quad*4 + r;
                float v = fmaxf(acc[mt][nt][r] + us2f(xs[rl * PITCH + col]), 0.f);
                unsigned short vb = f2us(v);
                hv[(size_t)(n0 + rl) * DD + col] = vb;
                xs[rl * PITCH + col] = vb;   // per-thread RMW, race-free
                int m = smol[rl];
                if (m != cur) { atomicAdd(&vbar[(size_t)cur * DD + col], run); run = 0.f; cur = m; }
                run += v;
            }
        atomicAdd(&vbar[(size_t)cur * DD + col], run);
    }
    if (do_z) {
        __syncthreads();
        mfma_store<4>(xs, WeP, 2, Zs, n0, tid);
        mfma_store<4>(xs, WeP, 3, Zd, n0, tid);
    }
}

// ---------------- phi_u fused: next-round yue/yuv + zero ebar/vbar ----------------
__global__ __launch_bounds__(256) void k_phi_u_f(
        const float* __restrict__ hu_in, const float* __restrict__ hu0,
        float* __restrict__ ebar, float* __restrict__ vbar,
        const float* __restrict__ Wu, const float* __restrict__ bu,
        const float* __restrict__ We, const float* __restrict__ be,
        const float* __restrict__ Wv, const float* __restrict__ bv,
        float* __restrict__ hu_out, float* __restrict__ dout,
        float* __restrict__ yue, float* __restrict__ yuv) {
    __shared__ float hrow[2 * DD];
    int tid = threadIdx.x;
    int ml = tid >> 7, d = tid & 127;
    int m = blockIdx.x * 2 + ml;
    float acc = bu[d];
    const float* segs[4] = { hu_in + m*DD, hu0 + m*DD, ebar + m*DD, vbar + m*DD };
    for (int s = 0; s < 4; s++) {
        const float* x = segs[s];
        const float* W = Wu + (s*DD)*DD + d;
        for (int k = 0; k < DD; k++)
            acc = fmaf(x[k], W[k*DD], acc);
    }
    float v = fmaxf(acc, 0.f);
    hu_out[m*DD + d] = v;
    dout[m*DD + d] = v;
    hrow[ml*DD + d] = v;
    __syncthreads();
    ebar[m*DD + d] = 0.f;
    vbar[m*DD + d] = 0.f;
    float ae = be[d], av = bv[d];
    for (int k = 0; k < DD; k++) {
        float h = hrow[ml*DD + k];
        ae = fmaf(h, We[(512 + k)*DD + d], ae);
        av = fmaf(h, Wv[(384 + k)*DD + d], av);
    }
    yue[m*DD + d] = ae;
    yuv[m*DD + d] = av;
}

// ---------------- launch ----------------

extern "C" void kernel_launch(void* const* d_in, const int* in_sizes, int n_in,
                              void* d_out, int out_size, void* d_ws, size_t ws_size,
                              hipStream_t stream) {
    const float* atoms = (const float*)d_in[0];
    const float* bo    = (const float*)d_in[1];
    const float* Wfe   = (const float*)d_in[2];
    const float* bfe   = (const float*)d_in[3];
    const float* Wfv   = (const float*)d_in[4];
    const float* bfv   = (const float*)d_in[5];
    const float* Wfu   = (const float*)d_in[6];
    const float* bfu   = (const float*)d_in[7];
    const float* We    = (const float*)d_in[8];
    const float* be    = (const float*)d_in[9];
    const float* Wv    = (const float*)d_in[10];
    const float* bv    = (const float*)d_in[11];
    const float* Wu    = (const float*)d_in[12];
    const float* bu    = (const float*)d_in[13];
    const int* bsrc    = (const int*)d_in[14];
    const int* bdst    = (const int*)d_in[15];
    const int* amol    = (const int*)d_in[16];
    const int* bmol    = (const int*)d_in[17];

    char* p = (char*)d_ws;
    auto alloc = [&](size_t bytes) {
        char* r = p;
        p += (bytes + 255) & ~(size_t)255;
        return r;
    };
    unsigned short* he     = (unsigned short*)alloc((size_t)N_BONDS * DD * 2);
    unsigned short* hv     = (unsigned short*)alloc((size_t)N_ATOMS * DD * 2);
    unsigned short* yv0    = (unsigned short*)alloc((size_t)N_ATOMS * DD * 2);
    unsigned short* Zs     = (unsigned short*)alloc((size_t)N_ATOMS * DD * 2);
    unsigned short* Zd     = (unsigned short*)alloc((size_t)N_ATOMS * DD * 2);
    unsigned short* ebar_i = (unsigned short*)alloc((size_t)N_ATOMS * DD * 2);
    unsigned short* WeP    = (unsigned short*)alloc((size_t)640 * DD * 2);
    unsigned short* WvP    = (unsigned short*)alloc((size_t)512 * DD * 2);
    int* deg      = (int*)alloc((size_t)N_ATOMS * 4);
    int* adj      = (int*)alloc((size_t)N_ATOMS * ADJW * 4);
    int* bmol_ptr = (int*)alloc((size_t)(N_MOLS + 1) * 4);
    int* amol_ptr = (int*)alloc((size_t)(N_MOLS + 1) * 4);
    float* node_sum = (float*)alloc((size_t)N_MOLS * DD * 4);
    float* hu0   = (float*)alloc((size_t)N_MOLS * DD * 4);
    float* huA   = (float*)alloc((size_t)N_MOLS * DD * 4);
    float* huB   = (float*)alloc((size_t)N_MOLS * DD * 4);
    float* ebar  = (float*)alloc((size_t)N_MOLS * DD * 4);
    float* vbar  = (float*)alloc((size_t)N_MOLS * DD * 4);
    float* yue   = (float*)alloc((size_t)N_MOLS * DD * 4);
    float* yuv   = (float*)alloc((size_t)N_MOLS * DD * 4);

    // ---- prep ----
    k_pack2<<<(640*DD + 512*DD)/256, 256, 0, stream>>>(We, Wv, WeP, WvP, deg);
    k_fill_fw<<<N_BONDS/256, 256, 0, stream>>>(bsrc, bdst, deg, adj);
    k_molptr2<<<2, 1024, 0, stream>>>(bmol, amol, bmol_ptr, amol_ptr);

    // ---- init ----
    k_nodes_f<<<N_ATOMS/128, 256, 0, stream>>>(atoms, Wfv, bfv, WvP, WeP,
                                               hv, yv0, Zs, Zd, node_sum);
    k_molsum_s<<<N_MOLS*2, 256, 0, stream>>>(hv, amol_ptr, node_sum, 2);
    k_mol_init_f<<<N_MOLS/2, 256, 0, stream>>>(node_sum, Wfu, bfu, We, be, Wv, bv,
                                               hu0, yue, yuv, ebar, vbar);

    const float* hu_in = hu0; float* hu_out = huA;

    for (int r = 0; r < REPEAT; r++) {
        if (r == 0)
            k_phi_e_r0<<<N_BONDS/64, 256, 0, stream>>>(he, bo, Wfe, bfe, Zs, Zd, WeP,
                                                       yue, bsrc, bdst, bmol, ebar);
        else
            k_phi_e_n<<<N_BONDS/64, 256, 0, stream>>>(he, bo, Wfe, bfe, Zs, Zd, WeP,
                                                      yue, bsrc, bdst, bmol, ebar);
        k_ebar<<<N_ATOMS/16, 256, 0, stream>>>(he, deg, adj, ebar_i);
        k_phi_v<<<N_ATOMS/64, 256, 0, stream>>>(hv, ebar_i, yv0, WvP, WeP, yuv,
                                                amol, vbar, Zs, Zd, (r < REPEAT - 1) ? 1 : 0);
        k_phi_u_f<<<N_MOLS/2, 256, 0, stream>>>(hu_in, hu0, ebar, vbar, Wu, bu,
                                                We, be, Wv, bv,
                                                hu_out, (float*)d_out, yue, yuv);
        hu_in = hu_out; hu_out = (hu_out == huA) ? huB : huA;
    }
}